// Round 11
// baseline (2554.833 us; speedup 1.0000x reference)
//
#include <hip/hip_runtime.h>

// PointNet++ SetAbstraction: FPS -> ball query -> grouped MLP(67->64->64->128, BN+ReLU) -> maxpool
// B=8, N=8192, S=2048, K=32, F=64.
//
// d_out: [8][2048][3] center_xyzs then [8][2048][128] center_feats (fp32).
// d_ws: 16576 floats of transposed weights.
//
// EXACTNESS INVARIANTS (validated R4..R10: absmax 7.8e-3 < 5.4e-2):
//   - discrete-decision math in contract(off) helpers; __f*_rn does NOT block FMA.
//   - np.sum last-axis n=3: FORWARD plain adds (x0+x1)+x2  [FPS dist, |c|^2, |x|^2]
//   - einsum dot: ascending FMA chain fma(c2,x2, fma(c1,x1, c0*x0))  [ball query]
//   - FPS argmax: u64 key (float_bits(bv)<<13)|(8191-idx); bv>=0 -> monotone bits;
//     pure max(key) == (max bv, tie -> min idx). Total order, any reduce shape.
//   - packed v2f +,*: identical rounding to scalar (R9/R10-validated).
//   - dual argmax chains: chain1 indices all > chain0; strict-> merge keeps
//     first-index semantics.
//
// PERF LESSONS:
//   R5: dynamically-indexed per-thread arrays get LDS-demoted — named vectors only.
//   R6/R7: __shfl_* lowers to ds_permute (LDS pipe) — use DPP for reductions.
//   R8: DPP reduce -> 1998 us @ 512thr. R9: 1024thr regressed (barrier scales).
//   R10: pk-math+dual-chains only -70us -> step is TAIL-bound (2-waves/SIMD
//        serialize 770cyc before barrier + LDS round trip + coord reads).
//   R11: FPS 256thr/4waves (halve pre-barrier serialization + skew, 4-slot
//        scan); sa_fused k-tile 32->16 (LDS 17.4->8.6KB, occupancy 2x).

#define NPTS 8192
#define SCTR 2048
#define NB   8
#define KNN  32
#define NF   64

typedef float v2f __attribute__((ext_vector_type(2)));

// d = (dx*dx + dy*dy) + dz*dz for TWO points, exact fp32 mul/add order,
// NO contraction (v_pk_add_f32 / v_pk_mul_f32 — same IEEE rounding as scalar).
__device__ __forceinline__ v2f fps_sqdist_v2(v2f px, v2f py, v2f pz,
                                             v2f lx, v2f ly, v2f lz) {
#pragma clang fp contract(off)
  v2f dx = px - lx;
  v2f dy = py - ly;
  v2f dz = pz - lz;
  v2f xx = dx * dx;
  v2f yy = dy * dy;
  v2f zz = dz * dz;
  return (xx + yy) + zz;
}

// (x*x + y*y) + z*z, NO contraction (np.sum forward order, n=3).
__device__ __forceinline__ float sumsq3(float x, float y, float z) {
#pragma clang fp contract(off)
  return (x * x + y * y) + z * z;
}

// Ball-query expanded form: (sc + sx) - 2*dot, NO contraction on the adds.
// dot = ascending-k FMA chain: fma(cz,z, fma(cy,y, cx*x)).
__device__ __forceinline__ float bq_d2(float sc, float sx,
                                       float cx, float cy, float cz,
                                       float x, float y, float z) {
#pragma clang fp contract(off)
  float dt = fmaf(cz, z, fmaf(cy, y, cx * x));
  return (sc + sx) - 2.0f * dt;
}

// u64 max with the partner lane's key fetched via DPP (VALU pipe, no LDS).
template <int CTRL>
__device__ __forceinline__ unsigned long long kmax_dpp(unsigned long long k) {
  int lo = (int)(unsigned int)(k & 0xFFFFFFFFull);
  int hi = (int)(unsigned int)(k >> 32);
  int slo = __builtin_amdgcn_update_dpp(lo, lo, CTRL, 0xF, 0xF, false);
  int shi = __builtin_amdgcn_update_dpp(hi, hi, CTRL, 0xF, 0xF, false);
  unsigned long long sk =
      ((unsigned long long)(unsigned int)shi << 32) | (unsigned int)slo;
  return sk > k ? sk : k;
}

// ---------------------------------------------------------------------------
// Kernel 1: blocks 0..7 = FPS (one block per batch, 256 thr = 4 waves = 1/SIMD,
// 32 points/thread in NAMED float4 registers, packed-f32 distances, dual
// argmax chains); blocks 8..72 = weight transpose. DPP reductions; LDS only
// for 4 wave-best slots, winner-coord broadcast, and writeback.
// ---------------------------------------------------------------------------
__global__ __launch_bounds__(256, 1) void fps_transpose_kernel(
    const float* __restrict__ xyzs,
    const float* __restrict__ w1, const float* __restrict__ w2, const float* __restrict__ w3,
    float* __restrict__ centers, float* __restrict__ wT)
{
  const int t = threadIdx.x;
  if (blockIdx.x >= NB) {
    int idx = (blockIdx.x - NB) * 256 + t;
    if (idx < 67*64) {
      int c = idx >> 6, o = idx & 63;
      wT[idx] = w1[o*67 + c];
    } else if (idx < 67*64 + 64*64) {
      int r = idx - 67*64; int c = r >> 6, o = r & 63;
      wT[idx] = w2[o*64 + c];
    } else if (idx < 67*64 + 64*64 + 64*128) {
      int r = idx - (67*64 + 64*64); int c = r >> 7, o = r & 127;
      wT[idx] = w3[o*64 + c];
    }
    return;
  }

  const int b = blockIdx.x;
  const float* xb = xyzs + (size_t)b * NPTS * 3;

  __shared__ float sX[NPTS], sY[NPTS], sZ[NPTS];         // 96 KB planar coords
  __shared__ unsigned long long redk[2][4];              // wave-best keys
  __shared__ int hist[SCTR];                             // 8 KB

  // One-time fill of the planar LDS copies (off the hot path).
  for (int i = t; i < NPTS; i += 256) {
    sX[i] = xb[3*i+0];
    sY[i] = xb[3*i+1];
    sZ[i] = xb[3*i+2];
  }
  if (t == 0) hist[0] = 0;   // reference: first center is index 0
  __syncthreads();

  const int t4 = 4 * t;

  // 32 loop-invariant points (8 quads strided 1024) in NAMED registers.
  const float4 xA = *(const float4*)(sX + 0    + t4);
  const float4 yA = *(const float4*)(sY + 0    + t4);
  const float4 zA = *(const float4*)(sZ + 0    + t4);
  const float4 xB = *(const float4*)(sX + 1024 + t4);
  const float4 yB = *(const float4*)(sY + 1024 + t4);
  const float4 zB = *(const float4*)(sZ + 1024 + t4);
  const float4 xC = *(const float4*)(sX + 2048 + t4);
  const float4 yC = *(const float4*)(sY + 2048 + t4);
  const float4 zC = *(const float4*)(sZ + 2048 + t4);
  const float4 xD = *(const float4*)(sX + 3072 + t4);
  const float4 yD = *(const float4*)(sY + 3072 + t4);
  const float4 zD = *(const float4*)(sZ + 3072 + t4);
  const float4 xE = *(const float4*)(sX + 4096 + t4);
  const float4 yE = *(const float4*)(sY + 4096 + t4);
  const float4 zE = *(const float4*)(sZ + 4096 + t4);
  const float4 xF = *(const float4*)(sX + 5120 + t4);
  const float4 yF = *(const float4*)(sY + 5120 + t4);
  const float4 zF = *(const float4*)(sZ + 5120 + t4);
  const float4 xG = *(const float4*)(sX + 6144 + t4);
  const float4 yG = *(const float4*)(sY + 6144 + t4);
  const float4 zG = *(const float4*)(sZ + 6144 + t4);
  const float4 xH = *(const float4*)(sX + 7168 + t4);
  const float4 yH = *(const float4*)(sY + 7168 + t4);
  const float4 zH = *(const float4*)(sZ + 7168 + t4);

  float4 mA = make_float4(1e10f,1e10f,1e10f,1e10f);
  float4 mB = mA, mC = mA, mD = mA, mE = mA, mF = mA, mG = mA, mH = mA;

  float lx = sX[0], ly = sY[0], lz = sZ[0];

#define FPS_QUAD(QX, QY, QZ, MV, QOFF, BV, BG)                                  \
  do {                                                                          \
    v2f d;                                                                      \
    d = fps_sqdist_v2((v2f){QX.x,QX.y}, (v2f){QY.x,QY.y}, (v2f){QZ.x,QZ.y},     \
                      lxv, lyv, lzv);                                           \
    MV.x = fminf(MV.x, d.x); if (MV.x > BV) { BV = MV.x; BG = (QOFF)+t4+0; }    \
    MV.y = fminf(MV.y, d.y); if (MV.y > BV) { BV = MV.y; BG = (QOFF)+t4+1; }    \
    d = fps_sqdist_v2((v2f){QX.z,QX.w}, (v2f){QY.z,QY.w}, (v2f){QZ.z,QZ.w},     \
                      lxv, lyv, lzv);                                           \
    MV.z = fminf(MV.z, d.x); if (MV.z > BV) { BV = MV.z; BG = (QOFF)+t4+2; }    \
    MV.w = fminf(MV.w, d.y); if (MV.w > BV) { BV = MV.w; BG = (QOFF)+t4+3; }    \
  } while (0)

  for (int s = 1; s < SCTR; ++s) {
    // Two independent chains (chain1 indices all exceed chain0's).
    float bv0 = -1.0f, bv1 = -1.0f; int bg0 = 0, bg1 = 0;
    {
      v2f lxv = {lx, lx}, lyv = {ly, ly}, lzv = {lz, lz};
      FPS_QUAD(xA, yA, zA, mA, 0,    bv0, bg0);
      FPS_QUAD(xB, yB, zB, mB, 1024, bv0, bg0);
      FPS_QUAD(xC, yC, zC, mC, 2048, bv0, bg0);
      FPS_QUAD(xD, yD, zD, mD, 3072, bv0, bg0);
      FPS_QUAD(xE, yE, zE, mE, 4096, bv1, bg1);
      FPS_QUAD(xF, yF, zF, mF, 5120, bv1, bg1);
      FPS_QUAD(xG, yG, zG, mG, 6144, bv1, bg1);
      FPS_QUAD(xH, yH, zH, mH, 7168, bv1, bg1);
    }
    float bv = bv0; int bg = bg0;
    if (bv1 > bv0) { bv = bv1; bg = bg1; }   // strict > keeps smaller-index chain

    // Pack: bv >= 0, so float bits are order-monotone.
    unsigned long long key =
        ((unsigned long long)__float_as_uint(bv) << 13) |
        (unsigned long long)(8191 - bg);

    // Wave-level max (VALU pipe); lane 63 holds the wave max after this.
    key = kmax_dpp<0x111>(key);   // row_shr:1
    key = kmax_dpp<0x112>(key);   // row_shr:2
    key = kmax_dpp<0x114>(key);   // row_shr:4
    key = kmax_dpp<0x118>(key);   // row_shr:8
    key = kmax_dpp<0x142>(key);   // row_bcast:15
    key = kmax_dpp<0x143>(key);   // row_bcast:31

    int pb = s & 1;   // double-buffered slots: one barrier per step
    if ((t & 63) == 63) redk[pb][t >> 6] = key;
    __syncthreads();

    // Cross-wave: lane reads slot (lane&3), then 2-hop mini-max over the
    // replicated 4-entry groups (quad_perm xor1, xor2) -> all lanes have max.
    unsigned long long k4 = redk[pb][t & 3];
    k4 = kmax_dpp<0xB1>(k4);      // quad_perm [1,0,3,2]
    k4 = kmax_dpp<0x4E>(k4);      // quad_perm [2,3,0,1]

    int i0 = 8191 - (int)(k4 & 0x1FFFull);
    // Winner coords: broadcast LDS reads (same address all lanes — free).
    lx = sX[i0]; ly = sY[i0]; lz = sZ[i0];
    if (t == 0) hist[s] = i0;
  }
#undef FPS_QUAD
  __syncthreads();

  for (int s = t; s < SCTR; s += 256) {
    int i = hist[s];
    float* o = centers + ((size_t)b * SCTR + s) * 3;
    o[0] = sX[i]; o[1] = sY[i]; o[2] = sZ[i];
  }
}

// ---------------------------------------------------------------------------
// Kernel 2: one 64-thread wave per center. Ball query (first K ascending
// index within radius, exact expanded-form d2) -> 32 indices; then TWO passes
// of 16 neighbors each through the 3-layer MLP (acc[2][8] per lane tile),
// maxpool accumulated in registers across passes. LDS halved vs R10
// (17.4 -> ~8.6 KB) to double blocks/CU for latency hiding.
// ---------------------------------------------------------------------------
__global__ __launch_bounds__(64) void sa_fused_kernel(
    const float* __restrict__ xyzs, const float* __restrict__ feats,
    const float* centers, const float* __restrict__ wT,
    const float* __restrict__ b1, const float* __restrict__ g1, const float* __restrict__ bt1,
    const float* __restrict__ m1, const float* __restrict__ v1,
    const float* __restrict__ b2, const float* __restrict__ g2, const float* __restrict__ bt2,
    const float* __restrict__ m2, const float* __restrict__ v2,
    const float* __restrict__ b3, const float* __restrict__ g3, const float* __restrict__ bt3,
    const float* __restrict__ m3, const float* __restrict__ v3,
    float* out_feats)
{
  constexpr float R2 = (float)(0.2 * 0.2);  // f32(0.04000000000000001) — matches ref predicate
  const int bid  = blockIdx.x;
  const int b    = bid >> 11;
  const int lane = threadIdx.x;
  const float* xb = xyzs + (size_t)b * NPTS * 3;
  const float* cp = centers + (size_t)bid * 3;
  float cx = cp[0], cy = cp[1], cz = cp[2];
  float sc = sumsq3(cx, cy, cz);

  __shared__ int   gidx[KNN];
  __shared__ float in_[16*67];   // 4288 B (stride 67 for gather, 65 for L2 out)
  __shared__ float y_[16*65];    // 4160 B

  // ---- ball query: first 32 in-radius points by ascending index ----
  int cnt = 0;
  for (int base = 0; base < NPTS && cnt < KNN; base += 64) {
    int n = base + lane;
    float x = xb[n*3+0], y = xb[n*3+1], z = xb[n*3+2];
    float sx = sumsq3(x, y, z);
    float d2 = bq_d2(sc, sx, cx, cy, cz, x, y, z);
    bool within = (d2 <= R2);
    unsigned long long mk = __ballot(within);
    int rank = __popcll(mk & ((1ull << lane) - 1ull));
    int slot = cnt + rank;
    if (within && slot < KNN) gidx[slot] = n;
    cnt += (int)__popcll(mk);
  }
  if (cnt > KNN) cnt = KNN;
  __syncthreads();

  const int g = lane >> 3;  // k-group: k16 = 2g, 2g+1
  const int h = lane & 7;   // o-group: o = 8h..8h+7
  const float* w1T = wT;                  // [67][64]
  const float* w2T = wT + 67*64;          // [64][64]
  const float* w3T = wT + 67*64 + 64*64;  // [64][128]

  float vmacc[2][8];
#pragma unroll
  for (int p=0;p<2;++p)
#pragma unroll
    for (int j=0;j<8;++j) vmacc[p][j] = 0.f;   // relu outputs >= 0

  for (int hh = 0; hh < 2; ++hh) {
    if (hh) __syncthreads();   // prior pass's in_ reads done before re-gather

    // ---- gather 16 rows: in_[k16][0..2] = xyz - center, [3..66] = feats ----
#pragma unroll 4
    for (int k16 = 0; k16 < 16; ++k16) {
      int kk = hh*16 + k16;
      int gk = (kk < cnt) ? gidx[kk] : -1;
      float fv = 0.f, xv = 0.f;
      if (gk >= 0) {
        fv = feats[((size_t)b * NPTS + gk) * NF + lane];
        if (lane < 3) xv = xb[gk*3 + lane] - cp[lane];  // exact single op
      }
      in_[k16*67 + 3 + lane] = fv;
      if (lane < 3) in_[k16*67 + lane] = xv;
    }
    __syncthreads();

    // ---- Layer 1: 67 -> 64 ----
    {
      float acc[2][8];
#pragma unroll
      for (int i=0;i<2;++i)
#pragma unroll
        for (int j=0;j<8;++j) acc[i][j]=0.f;
      for (int c = 0; c < 67; ++c) {
        float a0 = in_[(2*g+0)*67 + c];
        float a1 = in_[(2*g+1)*67 + c];
        const float* wr = w1T + c*64 + 8*h;
        float4 wv0 = *(const float4*)(wr);
        float4 wv1 = *(const float4*)(wr + 4);
        float wj[8] = {wv0.x,wv0.y,wv0.z,wv0.w,wv1.x,wv1.y,wv1.z,wv1.w};
#pragma unroll
        for (int j=0;j<8;++j) {
          acc[0][j] = fmaf(a0, wj[j], acc[0][j]);
          acc[1][j] = fmaf(a1, wj[j], acc[1][j]);
        }
      }
      float scl[8], shf[8];
#pragma unroll
      for (int j=0;j<8;++j) {
        int o = 8*h + j;
        float r = g1[o] * rsqrtf(v1[o] + 1e-5f);
        scl[j] = r;
        shf[j] = (b1[o] - m1[o]) * r + bt1[o];
      }
#pragma unroll
      for (int i=0;i<2;++i) {
        int k = 2*g + i;
#pragma unroll
        for (int j=0;j<8;++j)
          y_[k*65 + 8*h + j] = fmaxf(fmaf(acc[i][j], scl[j], shf[j]), 0.f);
      }
    }
    __syncthreads();

    // ---- Layer 2: 64 -> 64 (reads y_, writes in_ at stride 65) ----
    {
      float acc[2][8];
#pragma unroll
      for (int i=0;i<2;++i)
#pragma unroll
        for (int j=0;j<8;++j) acc[i][j]=0.f;
      for (int c = 0; c < 64; ++c) {
        float a0 = y_[(2*g+0)*65 + c];
        float a1 = y_[(2*g+1)*65 + c];
        const float* wr = w2T + c*64 + 8*h;
        float4 wv0 = *(const float4*)(wr);
        float4 wv1 = *(const float4*)(wr + 4);
        float wj[8] = {wv0.x,wv0.y,wv0.z,wv0.w,wv1.x,wv1.y,wv1.z,wv1.w};
#pragma unroll
        for (int j=0;j<8;++j) {
          acc[0][j] = fmaf(a0, wj[j], acc[0][j]);
          acc[1][j] = fmaf(a1, wj[j], acc[1][j]);
        }
      }
      float scl[8], shf[8];
#pragma unroll
      for (int j=0;j<8;++j) {
        int o = 8*h + j;
        float r = g2[o] * rsqrtf(v2[o] + 1e-5f);
        scl[j] = r;
        shf[j] = (b2[o] - m2[o]) * r + bt2[o];
      }
      __syncthreads();  // all y_ reads done before in_ overwrite ordering
#pragma unroll
      for (int i=0;i<2;++i) {
        int k = 2*g + i;
#pragma unroll
        for (int j=0;j<8;++j)
          in_[k*65 + 8*h + j] = fmaxf(fmaf(acc[i][j], scl[j], shf[j]), 0.f);
      }
    }
    __syncthreads();

    // ---- Layer 3: 64 -> 128 in two o-passes, BN+ReLU, register maxpool ----
    for (int p = 0; p < 2; ++p) {
      float acc[2][8];
#pragma unroll
      for (int i=0;i<2;++i)
#pragma unroll
        for (int j=0;j<8;++j) acc[i][j]=0.f;
      for (int c = 0; c < 64; ++c) {
        float a0 = in_[(2*g+0)*65 + c];
        float a1 = in_[(2*g+1)*65 + c];
        const float* wr = w3T + c*128 + p*64 + 8*h;
        float4 wv0 = *(const float4*)(wr);
        float4 wv1 = *(const float4*)(wr + 4);
        float wj[8] = {wv0.x,wv0.y,wv0.z,wv0.w,wv1.x,wv1.y,wv1.z,wv1.w};
#pragma unroll
        for (int j=0;j<8;++j) {
          acc[0][j] = fmaf(a0, wj[j], acc[0][j]);
          acc[1][j] = fmaf(a1, wj[j], acc[1][j]);
        }
      }
      float scl[8], shf[8];
#pragma unroll
      for (int j=0;j<8;++j) {
        int o = p*64 + 8*h + j;
        float r = g3[o] * rsqrtf(v3[o] + 1e-5f);
        scl[j] = r;
        shf[j] = (b3[o] - m3[o]) * r + bt3[o];
      }
#pragma unroll
      for (int j=0;j<8;++j) {
        float q0 = fmaxf(fmaf(acc[0][j], scl[j], shf[j]), 0.f);
        float q1 = fmaxf(fmaf(acc[1][j], scl[j], shf[j]), 0.f);
        vmacc[p][j] = fmaxf(vmacc[p][j], fmaxf(q0, q1));
      }
    }
  }

  // ---- maxpool across k-groups (lanes with same h) and store ----
#pragma unroll
  for (int mk = 8; mk < 64; mk <<= 1) {
#pragma unroll
    for (int p=0;p<2;++p)
#pragma unroll
      for (int j=0;j<8;++j)
        vmacc[p][j] = fmaxf(vmacc[p][j], __shfl_xor(vmacc[p][j], mk));
  }
  if (g == 0) {
#pragma unroll
    for (int p=0;p<2;++p) {
      float* dst = out_feats + (size_t)bid*128 + p*64 + 8*h;
      *(float4*)dst       = make_float4(vmacc[p][0],vmacc[p][1],vmacc[p][2],vmacc[p][3]);
      *(float4*)(dst + 4) = make_float4(vmacc[p][4],vmacc[p][5],vmacc[p][6],vmacc[p][7]);
    }
  }
}

// ---------------------------------------------------------------------------
extern "C" void kernel_launch(void* const* d_in, const int* in_sizes, int n_in,
                              void* d_out, int out_size, void* d_ws, size_t ws_size,
                              hipStream_t stream) {
  const float* xyzs  = (const float*)d_in[0];
  const float* feats = (const float*)d_in[1];
  const float* w1  = (const float*)d_in[2];
  const float* b1  = (const float*)d_in[3];
  const float* g1  = (const float*)d_in[4];
  const float* bt1 = (const float*)d_in[5];
  const float* m1  = (const float*)d_in[6];
  const float* v1  = (const float*)d_in[7];
  const float* w2  = (const float*)d_in[8];
  const float* b2  = (const float*)d_in[9];
  const float* g2  = (const float*)d_in[10];
  const float* bt2 = (const float*)d_in[11];
  const float* m2  = (const float*)d_in[12];
  const float* v2  = (const float*)d_in[13];
  const float* w3  = (const float*)d_in[14];
  const float* b3  = (const float*)d_in[15];
  const float* g3  = (const float*)d_in[16];
  const float* bt3 = (const float*)d_in[17];
  const float* m3  = (const float*)d_in[18];
  const float* v3  = (const float*)d_in[19];

  float* out       = (float*)d_out;
  float* centers   = out;                          // [8][2048][3]
  float* out_feats = out + (size_t)NB * SCTR * 3;  // [8][2048][128]
  float* wT        = (float*)d_ws;                 // 16576 floats

  // blocks 0..7: FPS; blocks 8..72: weight transpose (65 blocks x 256 thr)
  hipLaunchKernelGGL(fps_transpose_kernel, dim3(NB + 65), dim3(256), 0, stream,
                     xyzs, w1, w2, w3, centers, wT);
  hipLaunchKernelGGL(sa_fused_kernel, dim3(NB * SCTR), dim3(64), 0, stream,
                     xyzs, feats, centers, wT,
                     b1, g1, bt1, m1, v1,
                     b2, g2, bt2, m2, v2,
                     b3, g3, bt3, m3, v3,
                     out_feats);
}

// Round 12
// 2362.026 us; speedup vs baseline: 1.0816x; 1.0816x over previous
//
#include <hip/hip_runtime.h>

// PointNet++ SetAbstraction: FPS -> ball query -> grouped MLP(67->64->64->128, BN+ReLU) -> maxpool
// B=8, N=8192, S=2048, K=32, F=64.
//
// d_out: [8][2048][3] center_xyzs then [8][2048][128] center_feats (fp32).
// d_ws: 16576 floats of transposed weights.
//
// EXACTNESS INVARIANTS (validated R4..R11: absmax 7.8e-3 < 5.4e-2):
//   - discrete-decision math in contract(off) helpers; __f*_rn does NOT block FMA.
//   - np.sum last-axis n=3: FORWARD plain adds (x0+x1)+x2  [FPS dist, |c|^2, |x|^2]
//   - einsum dot: ascending FMA chain fma(c2,x2, fma(c1,x1, c0*x0))  [ball query]
//   - FPS argmax: u64 key (float_bits(bv)<<13)|(8191-idx); bv>=0 -> monotone bits;
//     pure max(key) == (max bv, tie -> min idx). Total order, any reduce shape.
//   - packed v2f +,*: identical rounding to scalar (R9/R10-validated).
//   - dual argmax chains: chain1 indices all > chain0; strict-> merge keeps
//     first-index semantics.
//
// PERF LESSONS:
//   R5: dynamically-indexed per-thread arrays get LDS-demoted — named vectors only.
//   R6/R7: __shfl_* lowers to ds_permute (LDS pipe) — use DPP for reductions.
//   R8/R9/R10/R11: FPS reduce on DPP; 256thr/1-wave-per-SIMD best (1832us);
//       barrier cost scales with wave count.
//   R11: sa k-16 two-pass REGRESSED (519->720): doubled gather/barrier overhead,
//       occupancy capped at 16 wg/CU. Structure reverted to R4 single-pass.
//   R12: sa c-loops get `#pragma unroll 4` — batch the 2 global weight-float4
//       loads + LDS reads across 4 iterations so vmcnt waits amortize (was
//       ~150-200 cyc dependent stall per iteration, VALUBusy 23.6%).

#define NPTS 8192
#define SCTR 2048
#define NB   8
#define KNN  32
#define NF   64

typedef float v2f __attribute__((ext_vector_type(2)));

// d = (dx*dx + dy*dy) + dz*dz for TWO points, exact fp32 mul/add order,
// NO contraction (v_pk_add_f32 / v_pk_mul_f32 — same IEEE rounding as scalar).
__device__ __forceinline__ v2f fps_sqdist_v2(v2f px, v2f py, v2f pz,
                                             v2f lx, v2f ly, v2f lz) {
#pragma clang fp contract(off)
  v2f dx = px - lx;
  v2f dy = py - ly;
  v2f dz = pz - lz;
  v2f xx = dx * dx;
  v2f yy = dy * dy;
  v2f zz = dz * dz;
  return (xx + yy) + zz;
}

// (x*x + y*y) + z*z, NO contraction (np.sum forward order, n=3).
__device__ __forceinline__ float sumsq3(float x, float y, float z) {
#pragma clang fp contract(off)
  return (x * x + y * y) + z * z;
}

// Ball-query expanded form: (sc + sx) - 2*dot, NO contraction on the adds.
// dot = ascending-k FMA chain: fma(cz,z, fma(cy,y, cx*x)).
__device__ __forceinline__ float bq_d2(float sc, float sx,
                                       float cx, float cy, float cz,
                                       float x, float y, float z) {
#pragma clang fp contract(off)
  float dt = fmaf(cz, z, fmaf(cy, y, cx * x));
  return (sc + sx) - 2.0f * dt;
}

// u64 max with the partner lane's key fetched via DPP (VALU pipe, no LDS).
template <int CTRL>
__device__ __forceinline__ unsigned long long kmax_dpp(unsigned long long k) {
  int lo = (int)(unsigned int)(k & 0xFFFFFFFFull);
  int hi = (int)(unsigned int)(k >> 32);
  int slo = __builtin_amdgcn_update_dpp(lo, lo, CTRL, 0xF, 0xF, false);
  int shi = __builtin_amdgcn_update_dpp(hi, hi, CTRL, 0xF, 0xF, false);
  unsigned long long sk =
      ((unsigned long long)(unsigned int)shi << 32) | (unsigned int)slo;
  return sk > k ? sk : k;
}

// ---------------------------------------------------------------------------
// Kernel 1 (R11-validated, unchanged): blocks 0..7 = FPS (256 thr = 4 waves =
// 1/SIMD, 32 pts/thread in NAMED float4 regs, packed-f32 distances, dual
// argmax chains, DPP reductions); blocks 8..72 = weight transpose.
// ---------------------------------------------------------------------------
__global__ __launch_bounds__(256, 1) void fps_transpose_kernel(
    const float* __restrict__ xyzs,
    const float* __restrict__ w1, const float* __restrict__ w2, const float* __restrict__ w3,
    float* __restrict__ centers, float* __restrict__ wT)
{
  const int t = threadIdx.x;
  if (blockIdx.x >= NB) {
    int idx = (blockIdx.x - NB) * 256 + t;
    if (idx < 67*64) {
      int c = idx >> 6, o = idx & 63;
      wT[idx] = w1[o*67 + c];
    } else if (idx < 67*64 + 64*64) {
      int r = idx - 67*64; int c = r >> 6, o = r & 63;
      wT[idx] = w2[o*64 + c];
    } else if (idx < 67*64 + 64*64 + 64*128) {
      int r = idx - (67*64 + 64*64); int c = r >> 7, o = r & 127;
      wT[idx] = w3[o*64 + c];
    }
    return;
  }

  const int b = blockIdx.x;
  const float* xb = xyzs + (size_t)b * NPTS * 3;

  __shared__ float sX[NPTS], sY[NPTS], sZ[NPTS];         // 96 KB planar coords
  __shared__ unsigned long long redk[2][4];              // wave-best keys
  __shared__ int hist[SCTR];                             // 8 KB

  for (int i = t; i < NPTS; i += 256) {
    sX[i] = xb[3*i+0];
    sY[i] = xb[3*i+1];
    sZ[i] = xb[3*i+2];
  }
  if (t == 0) hist[0] = 0;   // reference: first center is index 0
  __syncthreads();

  const int t4 = 4 * t;

  // 32 loop-invariant points (8 quads strided 1024) in NAMED registers.
  const float4 xA = *(const float4*)(sX + 0    + t4);
  const float4 yA = *(const float4*)(sY + 0    + t4);
  const float4 zA = *(const float4*)(sZ + 0    + t4);
  const float4 xB = *(const float4*)(sX + 1024 + t4);
  const float4 yB = *(const float4*)(sY + 1024 + t4);
  const float4 zB = *(const float4*)(sZ + 1024 + t4);
  const float4 xC = *(const float4*)(sX + 2048 + t4);
  const float4 yC = *(const float4*)(sY + 2048 + t4);
  const float4 zC = *(const float4*)(sZ + 2048 + t4);
  const float4 xD = *(const float4*)(sX + 3072 + t4);
  const float4 yD = *(const float4*)(sY + 3072 + t4);
  const float4 zD = *(const float4*)(sZ + 3072 + t4);
  const float4 xE = *(const float4*)(sX + 4096 + t4);
  const float4 yE = *(const float4*)(sY + 4096 + t4);
  const float4 zE = *(const float4*)(sZ + 4096 + t4);
  const float4 xF = *(const float4*)(sX + 5120 + t4);
  const float4 yF = *(const float4*)(sY + 5120 + t4);
  const float4 zF = *(const float4*)(sZ + 5120 + t4);
  const float4 xG = *(const float4*)(sX + 6144 + t4);
  const float4 yG = *(const float4*)(sY + 6144 + t4);
  const float4 zG = *(const float4*)(sZ + 6144 + t4);
  const float4 xH = *(const float4*)(sX + 7168 + t4);
  const float4 yH = *(const float4*)(sY + 7168 + t4);
  const float4 zH = *(const float4*)(sZ + 7168 + t4);

  float4 mA = make_float4(1e10f,1e10f,1e10f,1e10f);
  float4 mB = mA, mC = mA, mD = mA, mE = mA, mF = mA, mG = mA, mH = mA;

  float lx = sX[0], ly = sY[0], lz = sZ[0];

#define FPS_QUAD(QX, QY, QZ, MV, QOFF, BV, BG)                                  \
  do {                                                                          \
    v2f d;                                                                      \
    d = fps_sqdist_v2((v2f){QX.x,QX.y}, (v2f){QY.x,QY.y}, (v2f){QZ.x,QZ.y},     \
                      lxv, lyv, lzv);                                           \
    MV.x = fminf(MV.x, d.x); if (MV.x > BV) { BV = MV.x; BG = (QOFF)+t4+0; }    \
    MV.y = fminf(MV.y, d.y); if (MV.y > BV) { BV = MV.y; BG = (QOFF)+t4+1; }    \
    d = fps_sqdist_v2((v2f){QX.z,QX.w}, (v2f){QY.z,QY.w}, (v2f){QZ.z,QZ.w},     \
                      lxv, lyv, lzv);                                           \
    MV.z = fminf(MV.z, d.x); if (MV.z > BV) { BV = MV.z; BG = (QOFF)+t4+2; }    \
    MV.w = fminf(MV.w, d.y); if (MV.w > BV) { BV = MV.w; BG = (QOFF)+t4+3; }    \
  } while (0)

  for (int s = 1; s < SCTR; ++s) {
    float bv0 = -1.0f, bv1 = -1.0f; int bg0 = 0, bg1 = 0;
    {
      v2f lxv = {lx, lx}, lyv = {ly, ly}, lzv = {lz, lz};
      FPS_QUAD(xA, yA, zA, mA, 0,    bv0, bg0);
      FPS_QUAD(xB, yB, zB, mB, 1024, bv0, bg0);
      FPS_QUAD(xC, yC, zC, mC, 2048, bv0, bg0);
      FPS_QUAD(xD, yD, zD, mD, 3072, bv0, bg0);
      FPS_QUAD(xE, yE, zE, mE, 4096, bv1, bg1);
      FPS_QUAD(xF, yF, zF, mF, 5120, bv1, bg1);
      FPS_QUAD(xG, yG, zG, mG, 6144, bv1, bg1);
      FPS_QUAD(xH, yH, zH, mH, 7168, bv1, bg1);
    }
    float bv = bv0; int bg = bg0;
    if (bv1 > bv0) { bv = bv1; bg = bg1; }   // strict > keeps smaller-index chain

    unsigned long long key =
        ((unsigned long long)__float_as_uint(bv) << 13) |
        (unsigned long long)(8191 - bg);

    key = kmax_dpp<0x111>(key);   // row_shr:1
    key = kmax_dpp<0x112>(key);   // row_shr:2
    key = kmax_dpp<0x114>(key);   // row_shr:4
    key = kmax_dpp<0x118>(key);   // row_shr:8
    key = kmax_dpp<0x142>(key);   // row_bcast:15
    key = kmax_dpp<0x143>(key);   // row_bcast:31

    int pb = s & 1;
    if ((t & 63) == 63) redk[pb][t >> 6] = key;
    __syncthreads();

    unsigned long long k4 = redk[pb][t & 3];
    k4 = kmax_dpp<0xB1>(k4);      // quad_perm [1,0,3,2]
    k4 = kmax_dpp<0x4E>(k4);      // quad_perm [2,3,0,1]

    int i0 = 8191 - (int)(k4 & 0x1FFFull);
    lx = sX[i0]; ly = sY[i0]; lz = sZ[i0];
    if (t == 0) hist[s] = i0;
  }
#undef FPS_QUAD
  __syncthreads();

  for (int s = t; s < SCTR; s += 256) {
    int i = hist[s];
    float* o = centers + ((size_t)b * SCTR + s) * 3;
    o[0] = sX[i]; o[1] = sY[i]; o[2] = sZ[i];
  }
}

// ---------------------------------------------------------------------------
// Kernel 2: one 64-thread wave per center — R4 single-pass k=32 structure
// (validated) + `#pragma unroll 4` on the c-loops so weight/LDS loads batch
// across iterations instead of stalling ~150-200 cyc per iteration.
// ---------------------------------------------------------------------------
__global__ __launch_bounds__(64) void sa_fused_kernel(
    const float* __restrict__ xyzs, const float* __restrict__ feats,
    const float* centers, const float* __restrict__ wT,
    const float* __restrict__ b1, const float* __restrict__ g1, const float* __restrict__ bt1,
    const float* __restrict__ m1, const float* __restrict__ v1,
    const float* __restrict__ b2, const float* __restrict__ g2, const float* __restrict__ bt2,
    const float* __restrict__ m2, const float* __restrict__ v2,
    const float* __restrict__ b3, const float* __restrict__ g3, const float* __restrict__ bt3,
    const float* __restrict__ m3, const float* __restrict__ v3,
    float* out_feats)
{
  constexpr float R2 = (float)(0.2 * 0.2);  // f32(0.04000000000000001) — matches ref predicate
  const int bid  = blockIdx.x;
  const int b    = bid >> 11;
  const int lane = threadIdx.x;
  const float* xb = xyzs + (size_t)b * NPTS * 3;
  const float* cp = centers + (size_t)bid * 3;
  float cx = cp[0], cy = cp[1], cz = cp[2];
  float sc = sumsq3(cx, cy, cz);

  __shared__ int   gidx[KNN];
  __shared__ float in_[32*67];   // stride 67 (conflict-free for the 4k in-reads)
  __shared__ float y_[32*65];    // stride 65

  // ---- ball query: first 32 in-radius points by ascending index ----
  int cnt = 0;
  for (int base = 0; base < NPTS && cnt < KNN; base += 64) {
    int n = base + lane;
    float x = xb[n*3+0], y = xb[n*3+1], z = xb[n*3+2];
    float sx = sumsq3(x, y, z);
    float d2 = bq_d2(sc, sx, cx, cy, cz, x, y, z);
    bool within = (d2 <= R2);
    unsigned long long mk = __ballot(within);
    int rank = __popcll(mk & ((1ull << lane) - 1ull));
    int slot = cnt + rank;
    if (within && slot < KNN) gidx[slot] = n;
    cnt += (int)__popcll(mk);
  }
  if (cnt > KNN) cnt = KNN;
  __syncthreads();

  // ---- gather: in_[k][0..2] = xyz - center, in_[k][3..66] = feats ----
#pragma unroll 4
  for (int k = 0; k < KNN; ++k) {
    int gk = (k < cnt) ? gidx[k] : -1;
    float fv = 0.f, xv = 0.f;
    if (gk >= 0) {
      fv = feats[((size_t)b * NPTS + gk) * NF + lane];
      if (lane < 3) xv = xb[gk*3 + lane] - cp[lane];  // exact single op
    }
    in_[k*67 + 3 + lane] = fv;
    if (lane < 3) in_[k*67 + lane] = xv;
  }
  __syncthreads();

  const int g = lane >> 3;  // k-group: k = 4g..4g+3
  const int h = lane & 7;   // o-group: o = 8h..8h+7
  const float* w1T = wT;                  // [67][64]
  const float* w2T = wT + 67*64;          // [64][64]
  const float* w3T = wT + 67*64 + 64*64;  // [64][128]

  // ---- Layer 1: 67 -> 64 ----
  {
    float acc[4][8];
#pragma unroll
    for (int i=0;i<4;++i)
#pragma unroll
      for (int j=0;j<8;++j) acc[i][j]=0.f;
#pragma unroll 4
    for (int c = 0; c < 67; ++c) {
      float a0 = in_[(4*g+0)*67 + c];
      float a1 = in_[(4*g+1)*67 + c];
      float a2 = in_[(4*g+2)*67 + c];
      float a3 = in_[(4*g+3)*67 + c];
      const float* wr = w1T + c*64 + 8*h;
      float4 wv0 = *(const float4*)(wr);
      float4 wv1 = *(const float4*)(wr + 4);
      float wj[8] = {wv0.x,wv0.y,wv0.z,wv0.w,wv1.x,wv1.y,wv1.z,wv1.w};
#pragma unroll
      for (int j=0;j<8;++j) {
        acc[0][j] = fmaf(a0, wj[j], acc[0][j]);
        acc[1][j] = fmaf(a1, wj[j], acc[1][j]);
        acc[2][j] = fmaf(a2, wj[j], acc[2][j]);
        acc[3][j] = fmaf(a3, wj[j], acc[3][j]);
      }
    }
    float scl[8], shf[8];
#pragma unroll
    for (int j=0;j<8;++j) {
      int o = 8*h + j;
      float r = g1[o] * rsqrtf(v1[o] + 1e-5f);
      scl[j] = r;
      shf[j] = (b1[o] - m1[o]) * r + bt1[o];
    }
#pragma unroll
    for (int i=0;i<4;++i) {
      int k = 4*g + i;
#pragma unroll
      for (int j=0;j<8;++j)
        y_[k*65 + 8*h + j] = fmaxf(fmaf(acc[i][j], scl[j], shf[j]), 0.f);
    }
  }
  __syncthreads();

  // ---- Layer 2: 64 -> 64 (reads y_, writes in_ reused at stride 65) ----
  {
    float acc[4][8];
#pragma unroll
    for (int i=0;i<4;++i)
#pragma unroll
      for (int j=0;j<8;++j) acc[i][j]=0.f;
#pragma unroll 4
    for (int c = 0; c < 64; ++c) {
      float a0 = y_[(4*g+0)*65 + c];
      float a1 = y_[(4*g+1)*65 + c];
      float a2 = y_[(4*g+2)*65 + c];
      float a3 = y_[(4*g+3)*65 + c];
      const float* wr = w2T + c*64 + 8*h;
      float4 wv0 = *(const float4*)(wr);
      float4 wv1 = *(const float4*)(wr + 4);
      float wj[8] = {wv0.x,wv0.y,wv0.z,wv0.w,wv1.x,wv1.y,wv1.z,wv1.w};
#pragma unroll
      for (int j=0;j<8;++j) {
        acc[0][j] = fmaf(a0, wj[j], acc[0][j]);
        acc[1][j] = fmaf(a1, wj[j], acc[1][j]);
        acc[2][j] = fmaf(a2, wj[j], acc[2][j]);
        acc[3][j] = fmaf(a3, wj[j], acc[3][j]);
      }
    }
    float scl[8], shf[8];
#pragma unroll
    for (int j=0;j<8;++j) {
      int o = 8*h + j;
      float r = g2[o] * rsqrtf(v2[o] + 1e-5f);
      scl[j] = r;
      shf[j] = (b2[o] - m2[o]) * r + bt2[o];
    }
    __syncthreads();  // order old in_ reads before overwrite
#pragma unroll
    for (int i=0;i<4;++i) {
      int k = 4*g + i;
#pragma unroll
      for (int j=0;j<8;++j)
        in_[k*65 + 8*h + j] = fmaxf(fmaf(acc[i][j], scl[j], shf[j]), 0.f);
    }
  }
  __syncthreads();

  // ---- Layer 3: 64 -> 128 in two o-passes, BN+ReLU, maxpool over k, store ----
  for (int p = 0; p < 2; ++p) {
    float acc[4][8];
#pragma unroll
    for (int i=0;i<4;++i)
#pragma unroll
      for (int j=0;j<8;++j) acc[i][j]=0.f;
#pragma unroll 4
    for (int c = 0; c < 64; ++c) {
      float a0 = in_[(4*g+0)*65 + c];
      float a1 = in_[(4*g+1)*65 + c];
      float a2 = in_[(4*g+2)*65 + c];
      float a3 = in_[(4*g+3)*65 + c];
      const float* wr = w3T + c*128 + p*64 + 8*h;
      float4 wv0 = *(const float4*)(wr);
      float4 wv1 = *(const float4*)(wr + 4);
      float wj[8] = {wv0.x,wv0.y,wv0.z,wv0.w,wv1.x,wv1.y,wv1.z,wv1.w};
#pragma unroll
      for (int j=0;j<8;++j) {
        acc[0][j] = fmaf(a0, wj[j], acc[0][j]);
        acc[1][j] = fmaf(a1, wj[j], acc[1][j]);
        acc[2][j] = fmaf(a2, wj[j], acc[2][j]);
        acc[3][j] = fmaf(a3, wj[j], acc[3][j]);
      }
    }
    float scl[8], shf[8];
#pragma unroll
    for (int j=0;j<8;++j) {
      int o = p*64 + 8*h + j;
      float r = g3[o] * rsqrtf(v3[o] + 1e-5f);
      scl[j] = r;
      shf[j] = (b3[o] - m3[o]) * r + bt3[o];
    }
    float vm[8];
#pragma unroll
    for (int j=0;j<8;++j) {
      float q0 = fmaxf(fmaf(acc[0][j], scl[j], shf[j]), 0.f);
      float q1 = fmaxf(fmaf(acc[1][j], scl[j], shf[j]), 0.f);
      float q2 = fmaxf(fmaf(acc[2][j], scl[j], shf[j]), 0.f);
      float q3 = fmaxf(fmaf(acc[3][j], scl[j], shf[j]), 0.f);
      vm[j] = fmaxf(fmaxf(q0,q1), fmaxf(q2,q3));
    }
#pragma unroll
    for (int mk = 8; mk < 64; mk <<= 1) {
#pragma unroll
      for (int j=0;j<8;++j) vm[j] = fmaxf(vm[j], __shfl_xor(vm[j], mk));
    }
    if (g == 0) {
      float* dst = out_feats + (size_t)bid*128 + p*64 + 8*h;
      *(float4*)dst       = make_float4(vm[0],vm[1],vm[2],vm[3]);
      *(float4*)(dst + 4) = make_float4(vm[4],vm[5],vm[6],vm[7]);
    }
  }
}

// ---------------------------------------------------------------------------
extern "C" void kernel_launch(void* const* d_in, const int* in_sizes, int n_in,
                              void* d_out, int out_size, void* d_ws, size_t ws_size,
                              hipStream_t stream) {
  const float* xyzs  = (const float*)d_in[0];
  const float* feats = (const float*)d_in[1];
  const float* w1  = (const float*)d_in[2];
  const float* b1  = (const float*)d_in[3];
  const float* g1  = (const float*)d_in[4];
  const float* bt1 = (const float*)d_in[5];
  const float* m1  = (const float*)d_in[6];
  const float* v1  = (const float*)d_in[7];
  const float* w2  = (const float*)d_in[8];
  const float* b2  = (const float*)d_in[9];
  const float* g2  = (const float*)d_in[10];
  const float* bt2 = (const float*)d_in[11];
  const float* m2  = (const float*)d_in[12];
  const float* v2  = (const float*)d_in[13];
  const float* w3  = (const float*)d_in[14];
  const float* b3  = (const float*)d_in[15];
  const float* g3  = (const float*)d_in[16];
  const float* bt3 = (const float*)d_in[17];
  const float* m3  = (const float*)d_in[18];
  const float* v3  = (const float*)d_in[19];

  float* out       = (float*)d_out;
  float* centers   = out;                          // [8][2048][3]
  float* out_feats = out + (size_t)NB * SCTR * 3;  // [8][2048][128]
  float* wT        = (float*)d_ws;                 // 16576 floats

  // blocks 0..7: FPS; blocks 8..72: weight transpose (65 blocks x 256 thr)
  hipLaunchKernelGGL(fps_transpose_kernel, dim3(NB + 65), dim3(256), 0, stream,
                     xyzs, w1, w2, w3, centers, wT);
  hipLaunchKernelGGL(sa_fused_kernel, dim3(NB * SCTR), dim3(64), 0, stream,
                     xyzs, feats, centers, wT,
                     b1, g1, bt1, m1, v1,
                     b2, g2, bt2, m2, v2,
                     b3, g3, bt3, m3, v3,
                     out_feats);
}